// Round 12
// baseline (1172.652 us; speedup 1.0000x reference)
//
#include <hip/hip_runtime.h>
#include <hip/hip_fp16.h>
#include <math.h>

typedef _Float16 half8 __attribute__((ext_vector_type(8)));
typedef float f32x4 __attribute__((ext_vector_type(4)));

#define W0F 0.09817477042468103f   // 2*pi/64

#if __has_builtin(__builtin_amdgcn_exp2f)
#define EXP2F __builtin_amdgcn_exp2f
#else
#define EXP2F exp2f
#endif
#if __has_builtin(__builtin_amdgcn_rcpf)
#define RCPF __builtin_amdgcn_rcpf
#else
#define RCPF(x) (1.f/(x))
#endif

// fast sigmoid/tanh via hw exp2+rcp (rel err ~1e-6)
__device__ __forceinline__ float sigf(float x){
  return RCPF(1.f + EXP2F(-1.442695041f*x));
}
__device__ __forceinline__ float tanh_fast(float x){
  float t = EXP2F(2.885390082f*x);
  return 1.f - 2.f*RCPF(t + 1.f);
}
__device__ __forceinline__ float lrelu(float x){ return (x>0.f)? x : 0.01f*x; }

// pack float -> (hi f16 in low16, lo f16 in high16)   (phase A staging only)
__device__ __forceinline__ uint32_t packhl(float x){
  __half h = __float2half(x);
  __half l = __float2half(x - __half2float(h));
  return (uint32_t)__half_as_ushort(h) | ((uint32_t)__half_as_ushort(l) << 16);
}

// 8 packed dwords (two uint4) -> hi-frag and lo-frag (half8)   (phase A only)
__device__ __forceinline__ void unpackA(const uint4 d0, const uint4 d1, half8& hi, half8& lo){
  union { half8 h; uint32_t u[4]; } H, L;
  H.u[0] = (d0.x & 0xffffu) | (d0.y << 16);
  H.u[1] = (d0.z & 0xffffu) | (d0.w << 16);
  H.u[2] = (d1.x & 0xffffu) | (d1.y << 16);
  H.u[3] = (d1.z & 0xffffu) | (d1.w << 16);
  L.u[0] = (d0.x >> 16) | (d0.y & 0xffff0000u);
  L.u[1] = (d0.z >> 16) | (d0.w & 0xffff0000u);
  L.u[2] = (d1.x >> 16) | (d1.y & 0xffff0000u);
  L.u[3] = (d1.z >> 16) | (d1.w & 0xffff0000u);
  hi = H.h; lo = L.h;
}

// 2-pass: A exact (hi+lo), B f16-rounded (phase A)
__device__ __forceinline__ f32x4 mfma2(half8 ah, half8 al, half8 bh, f32x4 c){
  c = __builtin_amdgcn_mfma_f32_16x16x32_f16(ah, bh, c, 0,0,0);
  c = __builtin_amdgcn_mfma_f32_16x16x32_f16(al, bh, c, 0,0,0);
  return c;
}

// ---- ws layout (halves) ----
// WH0 hi@0 lo@65536 ; WI1 hi@131072 lo@196608 ; WH1 hi@262144 lo@327680
// FC1 hi@393216 lo@409600 ; TP1 hi@425984 lo@688128 ; total 950272 halves (1.86MB)
__global__ __launch_bounds__(256) void convert_w(
    const float* __restrict__ w_hh0, const float* __restrict__ w_ih1,
    const float* __restrict__ w_hh1, const float* __restrict__ fc1_w,
    const float* __restrict__ tp1_w, __half* __restrict__ wsH)
{
  int c = blockIdx.x*256 + threadIdx.x;   // 59392 chunks of 8 elems
  const float* src; size_t dhi, dlo; int n, k, K;
  if (c < 24576){
    int m = c >> 13; int q = c & 8191;
    src = (m==0)? w_hh0 : ((m==1)? w_ih1 : w_hh1); K = 128;
    dhi = (size_t)m*131072 + (size_t)q*8; dlo = dhi + 65536;
    int tile = q >> 8, ks = (q >> 6) & 3, lane = q & 63;
    n = tile*16 + (lane & 15); k = ks*32 + (lane >> 4)*8;
  } else if (c < 26624){
    int q = c - 24576; src = fc1_w; K = 128;
    dhi = 393216 + (size_t)q*8; dlo = 409600 + (size_t)q*8;
    int tile = q >> 8, ks = (q >> 6) & 3, lane = q & 63;
    n = tile*16 + (lane & 15); k = ks*32 + (lane >> 4)*8;
  } else {
    int q = c - 26624; src = tp1_w; K = 1024;
    dhi = 425984 + (size_t)q*8; dlo = 688128 + (size_t)q*8;
    int tile = q >> 11, ks = (q >> 6) & 31, lane = q & 63;
    n = tile*16 + (lane & 15); k = ks*32 + (lane >> 4)*8;
  }
  float4 a = *(const float4*)(src + (size_t)n*K + k);
  float4 b = *(const float4*)(src + (size_t)n*K + k + 4);
  float vv[8] = {a.x,a.y,a.z,a.w,b.x,b.y,b.z,b.w};
  union { uint4 u; unsigned short s[8]; } HI, LO;
  #pragma unroll
  for (int j = 0; j < 8; ++j){
    __half hh = __float2half(vv[j]);
    __half ll = __float2half(vv[j] - __half2float(hh));
    HI.s[j] = __half_as_ushort(hh);
    LO.s[j] = __half_as_ushort(ll);
  }
  *(uint4*)(wsH + dhi) = HI.u;
  *(uint4*)(wsH + dlo) = LO.u;
}

// M=32/block, 256 blocks, 1 block/CU. POOL phases: big@0(33792) med@33792(16384)
// LSTM: h0h@0 [32][136]h (8704) | h1h@8704 | c0s@17408 (18432) | c1s@35840
//       | fc2p@54272 [32][8]f
// ALL LSTM B-fragments pinned in 192 AGPRs ("a" constraint — arch VGPRs stay free;
// v9's "+v" pin forced them into the 128-wide VGPR class and spilled ~66 regs).
__global__ __attribute__((amdgpu_flat_work_group_size(512,512), amdgpu_waves_per_eu(2,2)))
void mkty_main(
    const float* __restrict__ data, const float* __restrict__ text_feature,
    const float* __restrict__ q_w, const float* __restrict__ q_b,
    const float* __restrict__ k_w, const float* __restrict__ k_b,
    const float* __restrict__ v_w, const float* __restrict__ v_b,
    const float* __restrict__ tp1_b,
    const float* __restrict__ tp2_w, const float* __restrict__ tp2_b,
    const float* __restrict__ g1_w, const float* __restrict__ g1_b,
    const float* __restrict__ g2_w, const float* __restrict__ g2_b,
    const float* __restrict__ w_ih0, const float* __restrict__ b_ih0,
    const float* __restrict__ b_hh0,
    const float* __restrict__ b_ih1, const float* __restrict__ b_hh1,
    const float* __restrict__ fc1_b,
    const float* __restrict__ fc2_w, const float* __restrict__ fc2_b,
    const __half* __restrict__ wsH, float* __restrict__ out)
{
  __shared__ float s_x[32][64];          // 8K
  __shared__ float s_gate[32][16];       // 2K
  __shared__ float s_rec[32][16];        // 2K
  __shared__ float s_res[32][16];        // 2K
  __shared__ float s_pred[32];
  __shared__ float ctab[64], stab[64];
  __shared__ __align__(16) unsigned char POOL[84992];  // >80K: 1 block/CU

  const int tid = threadIdx.x;
  const int w = tid >> 6, l = tid & 63;
  const int lm = l & 15, lq = l >> 4;
  const int s0blk = blockIdx.x * 32;

  { int s = tid >> 4, j = (tid*4) & 63;
    *(float4*)&s_x[s][j] = *(const float4*)(data + (size_t)(s0blk+s)*64 + j); }
  if (tid < 64){ float sv,cv; sincosf((float)tid*W0F,&sv,&cv);
    stab[tid] = (tid==32)?0.f:sv; ctab[tid]=cv; }
  __syncthreads();

  // ================= Phase A: h256 = lrelu(tf @ tp1_w^T + b1)  (MFMA, B f16-hi) =======
  {
    float* h256 = (float*)POOL;               // [32][260]
    uint32_t* tfp = (uint32_t*)(POOL + 33792);// [32][68] packed hi/lo
    const half8* T1h = (const half8*)(wsH + 425984);
    const int t0 = 2*w;
    f32x4 acc[2][2];
    #pragma unroll
    for (int mt=0; mt<2; ++mt)
      #pragma unroll
      for (int nt=0; nt<2; ++nt){ f32x4 z = {0.f,0.f,0.f,0.f}; acc[mt][nt] = z; }
    for (int kc = 0; kc < 1024; kc += 64){
      __syncthreads();
      { int s = tid >> 4, j0 = (tid & 15)*4;
        float4 v = *(const float4*)(text_feature + (size_t)(s0blk+s)*1024 + kc + j0);
        uint4 p; p.x = packhl(v.x); p.y = packhl(v.y); p.z = packhl(v.z); p.w = packhl(v.w);
        *(uint4*)&tfp[s*68 + j0] = p; }
      __syncthreads();
      #pragma unroll
      for (int ks = 0; ks < 2; ++ks){
        half8 Ah[2], Al[2];
        #pragma unroll
        for (int mt = 0; mt < 2; ++mt){
          const uint32_t* pp = &tfp[(mt*16+lm)*68 + ks*32 + lq*8];
          unpackA(*(const uint4*)pp, *(const uint4*)(pp+4), Ah[mt], Al[mt]);
        }
        int ksg = (kc >> 5) + ks;
        #pragma unroll
        for (int nt = 0; nt < 2; ++nt){
          int ci = ((t0+nt)*32 + ksg)*64 + l;
          half8 bh = T1h[ci];
          #pragma unroll
          for (int mt = 0; mt < 2; ++mt)
            acc[mt][nt] = mfma2(Ah[mt],Al[mt],bh,acc[mt][nt]);
        }
      }
    }
    #pragma unroll
    for (int nt = 0; nt < 2; ++nt){
      int n = (t0+nt)*16 + lm;
      float bb = tp1_b[n];
      #pragma unroll
      for (int mt = 0; mt < 2; ++mt)
        #pragma unroll
        for (int r = 0; r < 4; ++r)
          h256[(mt*16 + lq*4 + r)*260 + n] = lrelu(acc[mt][nt][r] + bb);
    }
  }
  __syncthreads();

  // ================= Phase B: tp = h256 @ tp2_w^T + b2  (VALU k-major) =================
  {
    const float* h256 = (const float*)POOL;
    int o = tid & 127, soct = tid >> 7, ss = soct*8;
    float acc8[8];
    #pragma unroll
    for (int i=0;i<8;++i) acc8[i]=0.f;
    const float4* w2r = (const float4*)(tp2_w + o*256);
    #pragma unroll 4
    for (int k4 = 0; k4 < 64; ++k4){
      float4 w4 = w2r[k4];
      #pragma unroll
      for (int i = 0; i < 8; ++i){
        float4 hv = *(const float4*)&h256[(ss+i)*260 + k4*4];
        acc8[i] += w4.x*hv.x; acc8[i] += w4.y*hv.y;
        acc8[i] += w4.z*hv.z; acc8[i] += w4.w*hv.w;
      }
    }
    __syncthreads();
    float* tpT = (float*)(POOL + 33792);   // [32][128]
    float bb = tp2_b[o];
    #pragma unroll
    for (int i=0;i<8;++i) tpT[(ss+i)*128 + o] = acc8[i] + bb;
  }
  __syncthreads();

  // ================= Phase C: DFT -> featT[64][32] =================
  {
    float* featT = (float*)POOL;
    #pragma unroll
    for (int i = 0; i < 2; ++i){
      int task = tid + 512*i;
      int s = task >> 5;
      int k = (task & 31) + 1;
      float re = 0.f, im = 0.f;
      #pragma unroll 8
      for (int n = 0; n < 64; ++n){
        float d = s_x[s][n];
        int m = (k*n) & 63;
        re += d*ctab[m]; im -= d*stab[m];
      }
      if (k == 32) im = 0.f;
      featT[(k-1)*32 + s] = sqrtf(re*re + im*im);
      featT[(31+k)*32 + s] = atan2f(im, re);
    }
  }
  __syncthreads();

  // ================= Phase D: Q,K,V ; QK = Q*K =================
  {
    const float* featT = (const float*)POOL;
    const float* tpT = (const float*)(POOL + 33792);
    float* QK = (float*)(POOL + 8192);
    float* V  = (float*)(POOL + 16384);
    #pragma unroll
    for (int i = 0; i < 4; ++i){
      int task = tid + 512*i;
      int s = task >> 6, o = task & 63;
      float q = q_b[o];
      const float* qwr = q_w + o*64;
      #pragma unroll 4
      for (int k = 0; k < 64; ++k) q += qwr[k]*featT[k*32 + s];
      float kk = k_b[o], vv = v_b[o];
      const float* kwr = k_w + o*128;
      const float* vwr = v_w + o*128;
      const float* tps = tpT + s*128;
      #pragma unroll 4
      for (int k = 0; k < 128; ++k){ kk += kwr[k]*tps[k]; vv += vwr[k]*tps[k]; }
      QK[s*64+o] = q*kk; V[s*64+o] = vv;
    }
  }
  __syncthreads();

  // ================= Phase E: adj = softmax(QK)*V (in-place in QK) =================
  if (tid < 32){
    float* QK = (float*)(POOL + 8192);
    const float* V = (const float*)(POOL + 16384);
    float mx = -1e30f;
    for (int o = 0; o < 64; ++o) mx = fmaxf(mx, QK[tid*64+o]);
    float sum = 0.f;
    for (int o = 0; o < 64; ++o){ float e = expf(QK[tid*64+o]-mx); QK[tid*64+o] = e; sum += e; }
    float inv = 1.f/sum;
    for (int o = 0; o < 64; ++o) QK[tid*64+o] *= inv*V[tid*64+o];
  }
  __syncthreads();

  // ================= Phase F: mid = lrelu(adj @ g1_w^T + b) =================
  {
    const float* ADJ = (const float*)(POOL + 8192);
    float* midT = (float*)(POOL + 33792);   // [32][128]
    int j = tid & 127, soct = tid >> 7, ss = soct*8;
    float accm[8];
    float bb = g1_b[j];
    #pragma unroll
    for (int i=0;i<8;++i) accm[i]=bb;
    const float* wr = g1_w + j*64;
    #pragma unroll 4
    for (int k = 0; k < 64; ++k){
      float ww = wr[k];
      #pragma unroll
      for (int i=0;i<8;++i) accm[i] += ww*ADJ[(ss+i)*64 + k];
    }
    #pragma unroll
    for (int i=0;i<8;++i) midT[(ss+i)*128 + j] = lrelu(accm[i]);
  }
  __syncthreads();

  // ================= Phase G: gate + recon =================
  {
    int s = tid >> 4, o = tid & 15;
    const float* midT = (const float*)(POOL + 33792);
    const float* ADJ = (const float*)(POOL + 8192);
    float acc = g2_b[o];
    const float* wr = g2_w + o*128;
    #pragma unroll 4
    for (int k = 0; k < 128; ++k) acc += wr[k]*midT[s*128 + k];
    float gate = sigf(acc);
    float sum = 0.f;
    float a32 = ADJ[s*64+31], p32 = ADJ[s*64+63];
    #pragma unroll
    for (int k = 1; k < 32; ++k){
      float amp = ADJ[s*64 + k-1];
      float ph  = ADJ[s*64 + 31+k];
      int m = (k*o) & 63;
      sum += amp*cosf(ph + (float)m*W0F);
    }
    float parity = (o&1)? -1.f : 1.f;
    s_gate[s][o] = gate;
    s_rec[s][o] = (2.f*sum + parity*a32*cosf(p32))*(1.f/64.f);
  }
  __syncthreads();

  // ===== LSTM prep: zero h planes (f16) + c planes (f32, stride-9 pad) =====
  { uint32_t* hz = (uint32_t*)POOL;
    for (int i = tid; i < 13568; i += 512) hz[i] = 0; }
  if (tid < 32) s_pred[tid] = s_x[tid][63];

  const int u = 16*w + lm;
  float bias0[4], wx0[4], bias1[4];
  #pragma unroll
  for (int T = 0; T < 4; ++T){
    int n = T*128 + u;
    bias0[T] = b_ih0[n] + b_hh0[n];
    wx0[T]   = w_ih0[n];
    bias1[T] = b_ih1[n] + b_hh1[n];
  }
  const float fb = fc1_b[u];
  const float wcol = fc2_w[u];
  const float fb2 = fc2_b[0];
  const half8* WH0h = (const half8*)(wsH);
  const half8* WI1h = (const half8*)(wsH + 131072);
  const half8* WH1h = (const half8*)(wsH + 262144);
  const half8* F1h  = (const half8*)(wsH + 393216);
  __half* h0h = (__half*)(POOL);            // [32][136]
  __half* h1h = (__half*)(POOL + 8704);     // [32][136]
  float*  c0s = (float*)(POOL + 17408);     // [tid][8] stride 9 (bank-spread)
  float*  c1s = (float*)(POOL + 35840);
  float*  fc2p = (float*)(POOL + 54272);    // [32][8]
  const int cbase = w*256 + l;

  // ---- permanent register cache: ALL LSTM B-fragments, pinned into AGPRs ----
  half8 wh0[16], wi1[16], wh1[16];
  #pragma unroll
  for (int q = 0; q < 16; ++q){       // q = nt*4 + ks
    int nt = q >> 2, ks = q & 3;
    int ci = nt*2048 + ks*64 + cbase;
    wh0[q] = WH0h[ci];
    wi1[q] = WI1h[ci];
    wh1[q] = WH1h[ci];
  }
  #pragma unroll
  for (int q = 0; q < 16; ++q)
    asm volatile("" : "+a"(wh0[q]), "+a"(wi1[q]), "+a"(wh1[q]));
  __syncthreads();

  for (int t = 0; t < 80; ++t){
    // ---- GEMM0: gates0 = h0 @ WH0^T + x*w_ih0 + b  (zero global loads) ----
    float xv[2][4];
    #pragma unroll
    for (int mt = 0; mt < 2; ++mt)
      #pragma unroll
      for (int r = 0; r < 4; ++r){
        int m = mt*16 + lq*4 + r;
        xv[mt][r] = (t < 64) ? s_x[m][t] : s_pred[m];
      }
    f32x4 acc0[2][4];
    #pragma unroll
    for (int nt = 0; nt < 4; ++nt)
      #pragma unroll
      for (int mt = 0; mt < 2; ++mt){
        f32x4 a;
        #pragma unroll
        for (int r = 0; r < 4; ++r) a[r] = bias0[nt] + wx0[nt]*xv[mt][r];
        acc0[mt][nt] = a;
      }
    #pragma unroll
    for (int ks = 0; ks < 4; ++ks){
      half8 Ah[2];
      #pragma unroll
      for (int mt = 0; mt < 2; ++mt)
        Ah[mt] = *(const half8*)&h0h[(mt*16+lm)*136 + ks*32 + lq*8];
      #pragma unroll
      for (int nt = 0; nt < 4; ++nt)
        #pragma unroll
        for (int mt = 0; mt < 2; ++mt)
          acc0[mt][nt] = __builtin_amdgcn_mfma_f32_16x16x32_f16(Ah[mt], wh0[nt*4+ks], acc0[mt][nt], 0,0,0);
    }
    __syncthreads();   // S1: all GEMM0 reads of h0h done
    #pragma unroll
    for (int mt = 0; mt < 2; ++mt)
      #pragma unroll
      for (int r = 0; r < 4; ++r){
        int cix = tid*9 + mt*4 + r;
        float gi = acc0[mt][0][r], gf = acc0[mt][1][r];
        float gg = acc0[mt][2][r], go = acc0[mt][3][r];
        float c = sigf(gf)*c0s[cix] + sigf(gi)*tanh_fast(gg);
        float h = sigf(go)*tanh_fast(c);
        c0s[cix] = c;
        h0h[(mt*16 + lq*4 + r)*136 + u] = __float2half(h);
      }
    __syncthreads();   // S2: new h0 visible
    // ---- GEMM1: gates1 = h0new @ WI1^T + h1 @ WH1^T + b (B all in AGPRs, 2 passes) ----
    f32x4 acc1[2][4];
    #pragma unroll
    for (int nt = 0; nt < 4; ++nt)
      #pragma unroll
      for (int mt = 0; mt < 2; ++mt){
        f32x4 a; float bb = bias1[nt];
        a[0]=bb; a[1]=bb; a[2]=bb; a[3]=bb;
        acc1[mt][nt] = a;
      }
    #pragma unroll
    for (int ks = 0; ks < 4; ++ks){
      half8 Ah[2];
      #pragma unroll
      for (int mt = 0; mt < 2; ++mt)
        Ah[mt] = *(const half8*)&h0h[(mt*16+lm)*136 + ks*32 + lq*8];
      #pragma unroll
      for (int nt = 0; nt < 4; ++nt)
        #pragma unroll
        for (int mt = 0; mt < 2; ++mt)
          acc1[mt][nt] = __builtin_amdgcn_mfma_f32_16x16x32_f16(Ah[mt], wi1[nt*4+ks], acc1[mt][nt], 0,0,0);
    }
    #pragma unroll
    for (int ks = 0; ks < 4; ++ks){
      half8 Ah[2];
      #pragma unroll
      for (int mt = 0; mt < 2; ++mt)
        Ah[mt] = *(const half8*)&h1h[(mt*16+lm)*136 + ks*32 + lq*8];
      #pragma unroll
      for (int nt = 0; nt < 4; ++nt)
        #pragma unroll
        for (int mt = 0; mt < 2; ++mt)
          acc1[mt][nt] = __builtin_amdgcn_mfma_f32_16x16x32_f16(Ah[mt], wh1[nt*4+ks], acc1[mt][nt], 0,0,0);
    }
    __syncthreads();   // S3: GEMM1 reads of h1h done
    #pragma unroll
    for (int mt = 0; mt < 2; ++mt)
      #pragma unroll
      for (int r = 0; r < 4; ++r){
        int cix = tid*9 + mt*4 + r;
        float gi = acc1[mt][0][r], gf = acc1[mt][1][r];
        float gg = acc1[mt][2][r], go = acc1[mt][3][r];
        float c = sigf(gf)*c1s[cix] + sigf(gi)*tanh_fast(gg);
        float h = sigf(go)*tanh_fast(c);
        c1s[cix] = c;
        h1h[(mt*16 + lq*4 + r)*136 + u] = __float2half(h);
      }
    __syncthreads();   // S4: new h1 visible

    if (t >= 64){
      // fc1: mid = lrelu(h1 @ fc1_w^T + b); fc2 via in-wave shuffle reduction
      f32x4 fa[2];
      #pragma unroll
      for (int mt = 0; mt < 2; ++mt){ f32x4 a; a[0]=fb;a[1]=fb;a[2]=fb;a[3]=fb; fa[mt]=a; }
      #pragma unroll
      for (int ks = 0; ks < 4; ++ks){
        half8 Ah[2];
        #pragma unroll
        for (int mt = 0; mt < 2; ++mt)
          Ah[mt] = *(const half8*)&h1h[(mt*16+lm)*136 + ks*32 + lq*8];
        int ci = (w*4 + ks)*64 + l;
        half8 bh = F1h[ci];
        #pragma unroll
        for (int mt = 0; mt < 2; ++mt)
          fa[mt] = __builtin_amdgcn_mfma_f32_16x16x32_f16(Ah[mt], bh, fa[mt], 0,0,0);
      }
      float pr[2][4];
      #pragma unroll
      for (int mt = 0; mt < 2; ++mt)
        #pragma unroll
        for (int r = 0; r < 4; ++r){
          float p = lrelu(fa[mt][r]) * wcol;
          p += __shfl_xor(p, 1, 16);
          p += __shfl_xor(p, 2, 16);
          p += __shfl_xor(p, 4, 16);
          p += __shfl_xor(p, 8, 16);
          pr[mt][r] = p;
        }
      if (lm == 0){
        #pragma unroll
        for (int mt = 0; mt < 2; ++mt)
          #pragma unroll
          for (int r = 0; r < 4; ++r)
            fc2p[(mt*16 + lq*4 + r)*8 + w] = pr[mt][r];
      }
      __syncthreads(); // S5
      if (tid < 32){
        float s = fb2;
        #pragma unroll
        for (int j = 0; j < 8; ++j) s += fc2p[tid*8 + j];
        s_pred[tid] = s;
        s_res[tid][t-64] = s;
      }
      __syncthreads(); // S6: s_pred visible for next step
    }
  }

  // ---- final combine ----
  {
    int s = tid >> 4, d = tid & 15;
    float g = s_gate[s][d];
    out[(size_t)blockIdx.x*512 + tid] = g*s_res[s][d] + (1.f - g)*s_rec[s][d];
  }
}

extern "C" void kernel_launch(void* const* d_in, const int* in_sizes, int n_in,
                              void* d_out, int out_size, void* d_ws, size_t ws_size,
                              hipStream_t stream){
  const float* data =(const float*)d_in[0];
  const float* tf   =(const float*)d_in[1];
  const float* q_w  =(const float*)d_in[2];  const float* q_b  =(const float*)d_in[3];
  const float* k_w  =(const float*)d_in[4];  const float* k_b  =(const float*)d_in[5];
  const float* v_w  =(const float*)d_in[6];  const float* v_b  =(const float*)d_in[7];
  const float* tp1_w=(const float*)d_in[8];  const float* tp1_b=(const float*)d_in[9];
  const float* tp2_w=(const float*)d_in[10]; const float* tp2_b=(const float*)d_in[11];
  const float* g1_w =(const float*)d_in[12]; const float* g1_b =(const float*)d_in[13];
  const float* g2_w =(const float*)d_in[14]; const float* g2_b =(const float*)d_in[15];
  const float* w_ih0=(const float*)d_in[16]; const float* b_ih0=(const float*)d_in[17];
  const float* w_hh0=(const float*)d_in[18]; const float* b_hh0=(const float*)d_in[19];
  const float* w_ih1=(const float*)d_in[20]; const float* b_ih1=(const float*)d_in[21];
  const float* w_hh1=(const float*)d_in[22]; const float* b_hh1=(const float*)d_in[23];
  const float* fc1_w=(const float*)d_in[24]; const float* fc1_b=(const float*)d_in[25];
  const float* fc2_w=(const float*)d_in[26]; const float* fc2_b=(const float*)d_in[27];
  float* out=(float*)d_out;
  __half* wsH = (__half*)d_ws;

  convert_w<<<232,256,0,stream>>>(w_hh0, w_ih1, w_hh1, fc1_w, tp1_w, wsH);
  mkty_main<<<256,512,0,stream>>>(data, tf, q_w,q_b, k_w,k_b, v_w,v_b,
                                  tp1_b, tp2_w,tp2_b, g1_w,g1_b, g2_w,g2_b,
                                  w_ih0,b_ih0,b_hh0, b_ih1,b_hh1,
                                  fc1_b, fc2_w,fc2_b, wsH, out);
}

// Round 13
// 858.233 us; speedup vs baseline: 1.3664x; 1.3664x over previous
//
#include <hip/hip_runtime.h>
#include <hip/hip_fp16.h>
#include <math.h>

typedef _Float16 half8 __attribute__((ext_vector_type(8)));
typedef float f32x4 __attribute__((ext_vector_type(4)));

#define W0F 0.09817477042468103f   // 2*pi/64

#if __has_builtin(__builtin_amdgcn_exp2f)
#define EXP2F __builtin_amdgcn_exp2f
#else
#define EXP2F exp2f
#endif
#if __has_builtin(__builtin_amdgcn_rcpf)
#define RCPF __builtin_amdgcn_rcpf
#else
#define RCPF(x) (1.f/(x))
#endif

// fast sigmoid/tanh via hw exp2+rcp (rel err ~1e-6)
__device__ __forceinline__ float sigf(float x){
  return RCPF(1.f + EXP2F(-1.442695041f*x));
}
__device__ __forceinline__ float tanh_fast(float x){
  float t = EXP2F(2.885390082f*x);
  return 1.f - 2.f*RCPF(t + 1.f);
}
__device__ __forceinline__ float lrelu(float x){ return (x>0.f)? x : 0.01f*x; }

// pack float -> (hi f16 in low16, lo f16 in high16)   (phase A staging only)
__device__ __forceinline__ uint32_t packhl(float x){
  __half h = __float2half(x);
  __half l = __float2half(x - __half2float(h));
  return (uint32_t)__half_as_ushort(h) | ((uint32_t)__half_as_ushort(l) << 16);
}

// 8 packed dwords (two uint4) -> hi-frag and lo-frag (half8)   (phase A only)
__device__ __forceinline__ void unpackA(const uint4 d0, const uint4 d1, half8& hi, half8& lo){
  union { half8 h; uint32_t u[4]; } H, L;
  H.u[0] = (d0.x & 0xffffu) | (d0.y << 16);
  H.u[1] = (d0.z & 0xffffu) | (d0.w << 16);
  H.u[2] = (d1.x & 0xffffu) | (d1.y << 16);
  H.u[3] = (d1.z & 0xffffu) | (d1.w << 16);
  L.u[0] = (d0.x >> 16) | (d0.y & 0xffff0000u);
  L.u[1] = (d0.z >> 16) | (d0.w & 0xffff0000u);
  L.u[2] = (d1.x >> 16) | (d1.y & 0xffff0000u);
  L.u[3] = (d1.z >> 16) | (d1.w & 0xffff0000u);
  hi = H.h; lo = L.h;
}

// 2-pass: A exact (hi+lo), B f16-rounded (phase A)
__device__ __forceinline__ f32x4 mfma2(half8 ah, half8 al, half8 bh, f32x4 c){
  c = __builtin_amdgcn_mfma_f32_16x16x32_f16(ah, bh, c, 0,0,0);
  c = __builtin_amdgcn_mfma_f32_16x16x32_f16(al, bh, c, 0,0,0);
  return c;
}

// ---- ws layout (halves) ----
// WH0 hi@0 lo@65536 ; WI1 hi@131072 lo@196608 ; WH1 hi@262144 lo@327680
// FC1 hi@393216 lo@409600 ; TP1 hi@425984 lo@688128 ; total 950272 halves (1.86MB)
__global__ __launch_bounds__(256) void convert_w(
    const float* __restrict__ w_hh0, const float* __restrict__ w_ih1,
    const float* __restrict__ w_hh1, const float* __restrict__ fc1_w,
    const float* __restrict__ tp1_w, __half* __restrict__ wsH)
{
  int c = blockIdx.x*256 + threadIdx.x;   // 59392 chunks of 8 elems
  const float* src; size_t dhi, dlo; int n, k, K;
  if (c < 24576){
    int m = c >> 13; int q = c & 8191;
    src = (m==0)? w_hh0 : ((m==1)? w_ih1 : w_hh1); K = 128;
    dhi = (size_t)m*131072 + (size_t)q*8; dlo = dhi + 65536;
    int tile = q >> 8, ks = (q >> 6) & 3, lane = q & 63;
    n = tile*16 + (lane & 15); k = ks*32 + (lane >> 4)*8;
  } else if (c < 26624){
    int q = c - 24576; src = fc1_w; K = 128;
    dhi = 393216 + (size_t)q*8; dlo = 409600 + (size_t)q*8;
    int tile = q >> 8, ks = (q >> 6) & 3, lane = q & 63;
    n = tile*16 + (lane & 15); k = ks*32 + (lane >> 4)*8;
  } else {
    int q = c - 26624; src = tp1_w; K = 1024;
    dhi = 425984 + (size_t)q*8; dlo = 688128 + (size_t)q*8;
    int tile = q >> 11, ks = (q >> 6) & 31, lane = q & 63;
    n = tile*16 + (lane & 15); k = ks*32 + (lane >> 4)*8;
  }
  float4 a = *(const float4*)(src + (size_t)n*K + k);
  float4 b = *(const float4*)(src + (size_t)n*K + k + 4);
  float vv[8] = {a.x,a.y,a.z,a.w,b.x,b.y,b.z,b.w};
  union { uint4 u; unsigned short s[8]; } HI, LO;
  #pragma unroll
  for (int j = 0; j < 8; ++j){
    __half hh = __float2half(vv[j]);
    __half ll = __float2half(vv[j] - __half2float(hh));
    HI.s[j] = __half_as_ushort(hh);
    LO.s[j] = __half_as_ushort(ll);
  }
  *(uint4*)(wsH + dhi) = HI.u;
  *(uint4*)(wsH + dlo) = LO.u;
}

// M=32/block, 256 blocks, 1 block/CU (v9 configuration restored).
// POOL phases: big@0(33792) med@33792(16384)
// LSTM: h0h@0 [32][136]h (8704) | h1h@8704 | c0s@17408 (18432) | c1s@35840
//       | fc2p@54272 [32][8]f
// ALL LSTM B-fragments pinned in 192 regs ("+v" — the only pin class that holds; v12's
// "+a" refetched per-step). ~66-reg spill accepted: 35MB scratch sits at the L2 edge
// and re-reads are L2-resident (v9: FETCH 104MB, 778us).
__global__ __attribute__((amdgpu_flat_work_group_size(512,512), amdgpu_waves_per_eu(2,2)))
void mkty_main(
    const float* __restrict__ data, const float* __restrict__ text_feature,
    const float* __restrict__ q_w, const float* __restrict__ q_b,
    const float* __restrict__ k_w, const float* __restrict__ k_b,
    const float* __restrict__ v_w, const float* __restrict__ v_b,
    const float* __restrict__ tp1_b,
    const float* __restrict__ tp2_w, const float* __restrict__ tp2_b,
    const float* __restrict__ g1_w, const float* __restrict__ g1_b,
    const float* __restrict__ g2_w, const float* __restrict__ g2_b,
    const float* __restrict__ w_ih0, const float* __restrict__ b_ih0,
    const float* __restrict__ b_hh0,
    const float* __restrict__ b_ih1, const float* __restrict__ b_hh1,
    const float* __restrict__ fc1_b,
    const float* __restrict__ fc2_w, const float* __restrict__ fc2_b,
    const __half* __restrict__ wsH, float* __restrict__ out)
{
  __shared__ float s_x[32][64];          // 8K
  __shared__ float s_gate[32][16];       // 2K
  __shared__ float s_rec[32][16];        // 2K
  __shared__ float s_res[32][16];        // 2K
  __shared__ float s_pred[32];
  __shared__ float ctab[64], stab[64];
  __shared__ __align__(16) unsigned char POOL[84992];  // >80K: 1 block/CU

  const int tid = threadIdx.x;
  const int w = tid >> 6, l = tid & 63;
  const int lm = l & 15, lq = l >> 4;
  const int s0blk = blockIdx.x * 32;

  { int s = tid >> 4, j = (tid*4) & 63;
    *(float4*)&s_x[s][j] = *(const float4*)(data + (size_t)(s0blk+s)*64 + j); }
  if (tid < 64){ float sv,cv; sincosf((float)tid*W0F,&sv,&cv);
    stab[tid] = (tid==32)?0.f:sv; ctab[tid]=cv; }
  __syncthreads();

  // ================= Phase A: h256 = lrelu(tf @ tp1_w^T + b1)  (MFMA, B f16-hi) =======
  {
    float* h256 = (float*)POOL;               // [32][260]
    uint32_t* tfp = (uint32_t*)(POOL + 33792);// [32][68] packed hi/lo
    const half8* T1h = (const half8*)(wsH + 425984);
    const int t0 = 2*w;
    f32x4 acc[2][2];
    #pragma unroll
    for (int mt=0; mt<2; ++mt)
      #pragma unroll
      for (int nt=0; nt<2; ++nt){ f32x4 z = {0.f,0.f,0.f,0.f}; acc[mt][nt] = z; }
    for (int kc = 0; kc < 1024; kc += 64){
      __syncthreads();
      { int s = tid >> 4, j0 = (tid & 15)*4;
        float4 v = *(const float4*)(text_feature + (size_t)(s0blk+s)*1024 + kc + j0);
        uint4 p; p.x = packhl(v.x); p.y = packhl(v.y); p.z = packhl(v.z); p.w = packhl(v.w);
        *(uint4*)&tfp[s*68 + j0] = p; }
      __syncthreads();
      #pragma unroll
      for (int ks = 0; ks < 2; ++ks){
        half8 Ah[2], Al[2];
        #pragma unroll
        for (int mt = 0; mt < 2; ++mt){
          const uint32_t* pp = &tfp[(mt*16+lm)*68 + ks*32 + lq*8];
          unpackA(*(const uint4*)pp, *(const uint4*)(pp+4), Ah[mt], Al[mt]);
        }
        int ksg = (kc >> 5) + ks;
        #pragma unroll
        for (int nt = 0; nt < 2; ++nt){
          int ci = ((t0+nt)*32 + ksg)*64 + l;
          half8 bh = T1h[ci];
          #pragma unroll
          for (int mt = 0; mt < 2; ++mt)
            acc[mt][nt] = mfma2(Ah[mt],Al[mt],bh,acc[mt][nt]);
        }
      }
    }
    #pragma unroll
    for (int nt = 0; nt < 2; ++nt){
      int n = (t0+nt)*16 + lm;
      float bb = tp1_b[n];
      #pragma unroll
      for (int mt = 0; mt < 2; ++mt)
        #pragma unroll
        for (int r = 0; r < 4; ++r)
          h256[(mt*16 + lq*4 + r)*260 + n] = lrelu(acc[mt][nt][r] + bb);
    }
  }
  __syncthreads();

  // ================= Phase B: tp = h256 @ tp2_w^T + b2  (VALU k-major) =================
  {
    const float* h256 = (const float*)POOL;
    int o = tid & 127, soct = tid >> 7, ss = soct*8;
    float acc8[8];
    #pragma unroll
    for (int i=0;i<8;++i) acc8[i]=0.f;
    const float4* w2r = (const float4*)(tp2_w + o*256);
    #pragma unroll 4
    for (int k4 = 0; k4 < 64; ++k4){
      float4 w4 = w2r[k4];
      #pragma unroll
      for (int i = 0; i < 8; ++i){
        float4 hv = *(const float4*)&h256[(ss+i)*260 + k4*4];
        acc8[i] += w4.x*hv.x; acc8[i] += w4.y*hv.y;
        acc8[i] += w4.z*hv.z; acc8[i] += w4.w*hv.w;
      }
    }
    __syncthreads();
    float* tpT = (float*)(POOL + 33792);   // [32][128]
    float bb = tp2_b[o];
    #pragma unroll
    for (int i=0;i<8;++i) tpT[(ss+i)*128 + o] = acc8[i] + bb;
  }
  __syncthreads();

  // ================= Phase C: DFT -> featT[64][32] =================
  {
    float* featT = (float*)POOL;
    #pragma unroll
    for (int i = 0; i < 2; ++i){
      int task = tid + 512*i;
      int s = task >> 5;
      int k = (task & 31) + 1;
      float re = 0.f, im = 0.f;
      #pragma unroll 8
      for (int n = 0; n < 64; ++n){
        float d = s_x[s][n];
        int m = (k*n) & 63;
        re += d*ctab[m]; im -= d*stab[m];
      }
      if (k == 32) im = 0.f;
      featT[(k-1)*32 + s] = sqrtf(re*re + im*im);
      featT[(31+k)*32 + s] = atan2f(im, re);
    }
  }
  __syncthreads();

  // ================= Phase D: Q,K,V ; QK = Q*K =================
  {
    const float* featT = (const float*)POOL;
    const float* tpT = (const float*)(POOL + 33792);
    float* QK = (float*)(POOL + 8192);
    float* V  = (float*)(POOL + 16384);
    #pragma unroll
    for (int i = 0; i < 4; ++i){
      int task = tid + 512*i;
      int s = task >> 6, o = task & 63;
      float q = q_b[o];
      const float* qwr = q_w + o*64;
      #pragma unroll 4
      for (int k = 0; k < 64; ++k) q += qwr[k]*featT[k*32 + s];
      float kk = k_b[o], vv = v_b[o];
      const float* kwr = k_w + o*128;
      const float* vwr = v_w + o*128;
      const float* tps = tpT + s*128;
      #pragma unroll 4
      for (int k = 0; k < 128; ++k){ kk += kwr[k]*tps[k]; vv += vwr[k]*tps[k]; }
      QK[s*64+o] = q*kk; V[s*64+o] = vv;
    }
  }
  __syncthreads();

  // ================= Phase E: adj = softmax(QK)*V (in-place in QK) =================
  if (tid < 32){
    float* QK = (float*)(POOL + 8192);
    const float* V = (const float*)(POOL + 16384);
    float mx = -1e30f;
    for (int o = 0; o < 64; ++o) mx = fmaxf(mx, QK[tid*64+o]);
    float sum = 0.f;
    for (int o = 0; o < 64; ++o){ float e = expf(QK[tid*64+o]-mx); QK[tid*64+o] = e; sum += e; }
    float inv = 1.f/sum;
    for (int o = 0; o < 64; ++o) QK[tid*64+o] *= inv*V[tid*64+o];
  }
  __syncthreads();

  // ================= Phase F: mid = lrelu(adj @ g1_w^T + b) =================
  {
    const float* ADJ = (const float*)(POOL + 8192);
    float* midT = (float*)(POOL + 33792);   // [32][128]
    int j = tid & 127, soct = tid >> 7, ss = soct*8;
    float accm[8];
    float bb = g1_b[j];
    #pragma unroll
    for (int i=0;i<8;++i) accm[i]=bb;
    const float* wr = g1_w + j*64;
    #pragma unroll 4
    for (int k = 0; k < 64; ++k){
      float ww = wr[k];
      #pragma unroll
      for (int i=0;i<8;++i) accm[i] += ww*ADJ[(ss+i)*64 + k];
    }
    #pragma unroll
    for (int i=0;i<8;++i) midT[(ss+i)*128 + j] = lrelu(accm[i]);
  }
  __syncthreads();

  // ================= Phase G: gate + recon =================
  {
    int s = tid >> 4, o = tid & 15;
    const float* midT = (const float*)(POOL + 33792);
    const float* ADJ = (const float*)(POOL + 8192);
    float acc = g2_b[o];
    const float* wr = g2_w + o*128;
    #pragma unroll 4
    for (int k = 0; k < 128; ++k) acc += wr[k]*midT[s*128 + k];
    float gate = sigf(acc);
    float sum = 0.f;
    float a32 = ADJ[s*64+31], p32 = ADJ[s*64+63];
    #pragma unroll
    for (int k = 1; k < 32; ++k){
      float amp = ADJ[s*64 + k-1];
      float ph  = ADJ[s*64 + 31+k];
      int m = (k*o) & 63;
      sum += amp*cosf(ph + (float)m*W0F);
    }
    float parity = (o&1)? -1.f : 1.f;
    s_gate[s][o] = gate;
    s_rec[s][o] = (2.f*sum + parity*a32*cosf(p32))*(1.f/64.f);
  }
  __syncthreads();

  // ===== LSTM prep: zero h planes (f16) + c planes (f32, stride-9 pad) =====
  { uint32_t* hz = (uint32_t*)POOL;
    for (int i = tid; i < 13568; i += 512) hz[i] = 0; }
  if (tid < 32) s_pred[tid] = s_x[tid][63];

  const int u = 16*w + lm;
  float bias0[4], wx0[4], bias1[4];
  #pragma unroll
  for (int T = 0; T < 4; ++T){
    int n = T*128 + u;
    bias0[T] = b_ih0[n] + b_hh0[n];
    wx0[T]   = w_ih0[n];
    bias1[T] = b_ih1[n] + b_hh1[n];
  }
  const float fb = fc1_b[u];
  const float wcol = fc2_w[u];
  const float fb2 = fc2_b[0];
  const half8* WH0h = (const half8*)(wsH);
  const half8* WI1h = (const half8*)(wsH + 131072);
  const half8* WH1h = (const half8*)(wsH + 262144);
  const half8* F1h  = (const half8*)(wsH + 393216);
  __half* h0h = (__half*)(POOL);            // [32][136]
  __half* h1h = (__half*)(POOL + 8704);     // [32][136]
  float*  c0s = (float*)(POOL + 17408);     // [tid][8] stride 9 (bank-spread)
  float*  c1s = (float*)(POOL + 35840);
  float*  fc2p = (float*)(POOL + 54272);    // [32][8]
  const int cbase = w*256 + l;

  // ---- permanent register cache: ALL LSTM B-fragments (3 x 16 half8 = 192 regs) ----
  half8 wh0[16], wi1[16], wh1[16];
  #pragma unroll
  for (int q = 0; q < 16; ++q){       // q = nt*4 + ks
    int nt = q >> 2, ks = q & 3;
    int ci = nt*2048 + ks*64 + cbase;
    wh0[q] = WH0h[ci];
    wi1[q] = WI1h[ci];
    wh1[q] = WH1h[ci];
  }
  #pragma unroll
  for (int q = 0; q < 16; ++q)
    asm volatile("" : "+v"(wh0[q]), "+v"(wi1[q]), "+v"(wh1[q]));
  __syncthreads();

  for (int t = 0; t < 80; ++t){
    // ---- GEMM0: gates0 = h0 @ WH0^T + x*w_ih0 + b  (zero global loads) ----
    float xv[2][4];
    #pragma unroll
    for (int mt = 0; mt < 2; ++mt)
      #pragma unroll
      for (int r = 0; r < 4; ++r){
        int m = mt*16 + lq*4 + r;
        xv[mt][r] = (t < 64) ? s_x[m][t] : s_pred[m];
      }
    f32x4 acc0[2][4];
    #pragma unroll
    for (int nt = 0; nt < 4; ++nt)
      #pragma unroll
      for (int mt = 0; mt < 2; ++mt){
        f32x4 a;
        #pragma unroll
        for (int r = 0; r < 4; ++r) a[r] = bias0[nt] + wx0[nt]*xv[mt][r];
        acc0[mt][nt] = a;
      }
    __builtin_amdgcn_s_setprio(1);
    #pragma unroll
    for (int ks = 0; ks < 4; ++ks){
      half8 Ah[2];
      #pragma unroll
      for (int mt = 0; mt < 2; ++mt)
        Ah[mt] = *(const half8*)&h0h[(mt*16+lm)*136 + ks*32 + lq*8];
      #pragma unroll
      for (int nt = 0; nt < 4; ++nt)
        #pragma unroll
        for (int mt = 0; mt < 2; ++mt)
          acc0[mt][nt] = __builtin_amdgcn_mfma_f32_16x16x32_f16(Ah[mt], wh0[nt*4+ks], acc0[mt][nt], 0,0,0);
    }
    __builtin_amdgcn_s_setprio(0);
    __syncthreads();   // S1: all GEMM0 reads of h0h done
    #pragma unroll
    for (int mt = 0; mt < 2; ++mt)
      #pragma unroll
      for (int r = 0; r < 4; ++r){
        int cix = tid*9 + mt*4 + r;
        float gi = acc0[mt][0][r], gf = acc0[mt][1][r];
        float gg = acc0[mt][2][r], go = acc0[mt][3][r];
        float c = sigf(gf)*c0s[cix] + sigf(gi)*tanh_fast(gg);
        float h = sigf(go)*tanh_fast(c);
        c0s[cix] = c;
        h0h[(mt*16 + lq*4 + r)*136 + u] = __float2half(h);
      }
    __syncthreads();   // S2: new h0 visible
    // ---- GEMM1: gates1 = h0new @ WI1^T + h1 @ WH1^T + b (B all in regs, 2 passes) ----
    f32x4 acc1[2][4];
    #pragma unroll
    for (int nt = 0; nt < 4; ++nt)
      #pragma unroll
      for (int mt = 0; mt < 2; ++mt){
        f32x4 a; float bb = bias1[nt];
        a[0]=bb; a[1]=bb; a[2]=bb; a[3]=bb;
        acc1[mt][nt] = a;
      }
    __builtin_amdgcn_s_setprio(1);
    #pragma unroll
    for (int ks = 0; ks < 4; ++ks){
      half8 Ah[2];
      #pragma unroll
      for (int mt = 0; mt < 2; ++mt)
        Ah[mt] = *(const half8*)&h0h[(mt*16+lm)*136 + ks*32 + lq*8];
      #pragma unroll
      for (int nt = 0; nt < 4; ++nt)
        #pragma unroll
        for (int mt = 0; mt < 2; ++mt)
          acc1[mt][nt] = __builtin_amdgcn_mfma_f32_16x16x32_f16(Ah[mt], wi1[nt*4+ks], acc1[mt][nt], 0,0,0);
    }
    #pragma unroll
    for (int ks = 0; ks < 4; ++ks){
      half8 Ah[2];
      #pragma unroll
      for (int mt = 0; mt < 2; ++mt)
        Ah[mt] = *(const half8*)&h1h[(mt*16+lm)*136 + ks*32 + lq*8];
      #pragma unroll
      for (int nt = 0; nt < 4; ++nt)
        #pragma unroll
        for (int mt = 0; mt < 2; ++mt)
          acc1[mt][nt] = __builtin_amdgcn_mfma_f32_16x16x32_f16(Ah[mt], wh1[nt*4+ks], acc1[mt][nt], 0,0,0);
    }
    __builtin_amdgcn_s_setprio(0);
    __syncthreads();   // S3: GEMM1 reads of h1h done
    #pragma unroll
    for (int mt = 0; mt < 2; ++mt)
      #pragma unroll
      for (int r = 0; r < 4; ++r){
        int cix = tid*9 + mt*4 + r;
        float gi = acc1[mt][0][r], gf = acc1[mt][1][r];
        float gg = acc1[mt][2][r], go = acc1[mt][3][r];
        float c = sigf(gf)*c1s[cix] + sigf(gi)*tanh_fast(gg);
        float h = sigf(go)*tanh_fast(c);
        c1s[cix] = c;
        h1h[(mt*16 + lq*4 + r)*136 + u] = __float2half(h);
      }
    __syncthreads();   // S4: new h1 visible

    if (t >= 64){
      // fc1: mid = lrelu(h1 @ fc1_w^T + b); fc2 via in-wave shuffle reduction
      f32x4 fa[2];
      #pragma unroll
      for (int mt = 0; mt < 2; ++mt){ f32x4 a; a[0]=fb;a[1]=fb;a[2]=fb;a[3]=fb; fa[mt]=a; }
      __builtin_amdgcn_s_setprio(1);
      #pragma unroll
      for (int ks = 0; ks < 4; ++ks){
        half8 Ah[2];
        #pragma unroll
        for (int mt = 0; mt < 2; ++mt)
          Ah[mt] = *(const half8*)&h1h[(mt*16+lm)*136 + ks*32 + lq*8];
        int ci = (w*4 + ks)*64 + l;
        half8 bh = F1h[ci];
        #pragma unroll
        for (int mt = 0; mt < 2; ++mt)
          fa[mt] = __builtin_amdgcn_mfma_f32_16x16x32_f16(Ah[mt], bh, fa[mt], 0,0,0);
      }
      __builtin_amdgcn_s_setprio(0);
      float pr[2][4];
      #pragma unroll
      for (int mt = 0; mt < 2; ++mt)
        #pragma unroll
        for (int r = 0; r < 4; ++r){
          float p = lrelu(fa[mt][r]) * wcol;
          p += __shfl_xor(p, 1, 16);
          p += __shfl_xor(p, 2, 16);
          p += __shfl_xor(p, 4, 16);
          p += __shfl_xor(p, 8, 16);
          pr[mt][r] = p;
        }
      if (lm == 0){
        #pragma unroll
        for (int mt = 0; mt < 2; ++mt)
          #pragma unroll
          for (int r = 0; r < 4; ++r)
            fc2p[(mt*16 + lq*4 + r)*8 + w] = pr[mt][r];
      }
      __syncthreads(); // S5
      if (tid < 32){
        float s = fb2;
        #pragma unroll
        for (int j = 0; j < 8; ++j) s += fc2p[tid*8 + j];
        s_pred[tid] = s;
        s_res[tid][t-64] = s;
      }
      __syncthreads(); // S6: s_pred visible for next step
    }
  }

  // ---- final combine ----
  {
    int s = tid >> 4, d = tid & 15;
    float g = s_gate[s][d];
    out[(size_t)blockIdx.x*512 + tid] = g*s_res[s][d] + (1.f - g)*s_rec[s][d];
  }
}

extern "C" void kernel_launch(void* const* d_in, const int* in_sizes, int n_in,
                              void* d_out, int out_size, void* d_ws, size_t ws_size,
                              hipStream_t stream){
  const float* data =(const float*)d_in[0];
  const float* tf   =(const float*)d_in[1];
  const float* q_w  =(const float*)d_in[2];  const float* q_b  =(const float*)d_in[3];
  const float* k_w  =(const float*)d_in[4];  const float* k_b  =(const float*)d_in[5];
  const float* v_w  =(const float*)d_in[6];  const float* v_b  =(const float*)d_in[7];
  const float* tp1_w=(const float*)d_in[8];  const float* tp1_b=(const float*)d_in[9];
  const float* tp2_w=(const float*)d_in[10]; const float* tp2_b=(const float*)d_in[11];
  const float* g1_w =(const float*)d_in[12]; const float* g1_b =(const float*)d_in[13];
  const float* g2_w =(const float*)d_in[14]; const float* g2_b =(const float*)d_in[15];
  const float* w_ih0=(const float*)d_in[16]; const float* b_ih0=(const float*)d_in[17];
  const float* w_hh0=(const float*)d_in[18]; const float* b_hh0=(const float*)d_in[19];
  const float* w_ih1=(const float*)d_in[20]; const float* b_ih1=(const float*)d_in[21];
  const float* w_hh1=(const float*)d_in[22]; const float* b_hh1=(const float*)d_in[23];
  const float* fc1_w=(const float*)d_in[24]; const float* fc1_b=(const float*)d_in[25];
  const float* fc2_w=(const float*)d_in[26]; const float* fc2_b=(const float*)d_in[27];
  float* out=(float*)d_out;
  __half* wsH = (__half*)d_ws;

  convert_w<<<232,256,0,stream>>>(w_hh0, w_ih1, w_hh1, fc1_w, tp1_w, wsH);
  mkty_main<<<256,512,0,stream>>>(data, tf, q_w,q_b, k_w,k_b, v_w,v_b,
                                  tp1_b, tp2_w,tp2_b, g1_w,g1_b, g2_w,g2_b,
                                  w_ih0,b_ih0,b_hh0, b_ih1,b_hh1,
                                  fc1_b, fc2_w,fc2_b, wsH, out);
}

// Round 14
// 830.902 us; speedup vs baseline: 1.4113x; 1.0329x over previous
//
#include <hip/hip_runtime.h>
#include <hip/hip_fp16.h>
#include <math.h>

typedef _Float16 half8 __attribute__((ext_vector_type(8)));
typedef float f32x4 __attribute__((ext_vector_type(4)));

#define W0F 0.09817477042468103f   // 2*pi/64

#if __has_builtin(__builtin_amdgcn_exp2f)
#define EXP2F __builtin_amdgcn_exp2f
#else
#define EXP2F exp2f
#endif
#if __has_builtin(__builtin_amdgcn_rcpf)
#define RCPF __builtin_amdgcn_rcpf
#else
#define RCPF(x) (1.f/(x))
#endif

// fast sigmoid/tanh via hw exp2+rcp (rel err ~1e-6)
__device__ __forceinline__ float sigf(float x){
  return RCPF(1.f + EXP2F(-1.442695041f*x));
}
__device__ __forceinline__ float tanh_fast(float x){
  float t = EXP2F(2.885390082f*x);
  return 1.f - 2.f*RCPF(t + 1.f);
}
__device__ __forceinline__ float lrelu(float x){ return (x>0.f)? x : 0.01f*x; }

// pack float -> (hi f16 in low16, lo f16 in high16)   (phase A staging only)
__device__ __forceinline__ uint32_t packhl(float x){
  __half h = __float2half(x);
  __half l = __float2half(x - __half2float(h));
  return (uint32_t)__half_as_ushort(h) | ((uint32_t)__half_as_ushort(l) << 16);
}

// 8 packed dwords (two uint4) -> hi-frag and lo-frag (half8)   (phase A only)
__device__ __forceinline__ void unpackA(const uint4 d0, const uint4 d1, half8& hi, half8& lo){
  union { half8 h; uint32_t u[4]; } H, L;
  H.u[0] = (d0.x & 0xffffu) | (d0.y << 16);
  H.u[1] = (d0.z & 0xffffu) | (d0.w << 16);
  H.u[2] = (d1.x & 0xffffu) | (d1.y << 16);
  H.u[3] = (d1.z & 0xffffu) | (d1.w << 16);
  L.u[0] = (d0.x >> 16) | (d0.y & 0xffff0000u);
  L.u[1] = (d0.z >> 16) | (d0.w & 0xffff0000u);
  L.u[2] = (d1.x >> 16) | (d1.y & 0xffff0000u);
  L.u[3] = (d1.z >> 16) | (d1.w & 0xffff0000u);
  hi = H.h; lo = L.h;
}

// 2-pass: A exact (hi+lo), B f16-rounded (phase A)
__device__ __forceinline__ f32x4 mfma2(half8 ah, half8 al, half8 bh, f32x4 c){
  c = __builtin_amdgcn_mfma_f32_16x16x32_f16(ah, bh, c, 0,0,0);
  c = __builtin_amdgcn_mfma_f32_16x16x32_f16(al, bh, c, 0,0,0);
  return c;
}

// ---- ws layout (halves) ----
// WH0 hi@0 lo@65536 ; WI1 hi@131072 lo@196608 ; WH1 hi@262144 lo@327680
// FC1 hi@393216 lo@409600 ; TP1 hi@425984 lo@688128 ; total 950272 halves (1.86MB)
// (lo planes of WH0/WI1/WH1/FC1/TP1 are written but no longer read — harmless)
__global__ __launch_bounds__(256) void convert_w(
    const float* __restrict__ w_hh0, const float* __restrict__ w_ih1,
    const float* __restrict__ w_hh1, const float* __restrict__ fc1_w,
    const float* __restrict__ tp1_w, __half* __restrict__ wsH)
{
  int c = blockIdx.x*256 + threadIdx.x;   // 59392 chunks of 8 elems
  const float* src; size_t dhi, dlo; int n, k, K;
  if (c < 24576){
    int m = c >> 13; int q = c & 8191;
    src = (m==0)? w_hh0 : ((m==1)? w_ih1 : w_hh1); K = 128;
    dhi = (size_t)m*131072 + (size_t)q*8; dlo = dhi + 65536;
    int tile = q >> 8, ks = (q >> 6) & 3, lane = q & 63;
    n = tile*16 + (lane & 15); k = ks*32 + (lane >> 4)*8;
  } else if (c < 26624){
    int q = c - 24576; src = fc1_w; K = 128;
    dhi = 393216 + (size_t)q*8; dlo = 409600 + (size_t)q*8;
    int tile = q >> 8, ks = (q >> 6) & 3, lane = q & 63;
    n = tile*16 + (lane & 15); k = ks*32 + (lane >> 4)*8;
  } else {
    int q = c - 26624; src = tp1_w; K = 1024;
    dhi = 425984 + (size_t)q*8; dlo = 688128 + (size_t)q*8;
    int tile = q >> 11, ks = (q >> 6) & 31, lane = q & 63;
    n = tile*16 + (lane & 15); k = ks*32 + (lane >> 4)*8;
  }
  float4 a = *(const float4*)(src + (size_t)n*K + k);
  float4 b = *(const float4*)(src + (size_t)n*K + k + 4);
  float vv[8] = {a.x,a.y,a.z,a.w,b.x,b.y,b.z,b.w};
  union { uint4 u; unsigned short s[8]; } HI, LO;
  #pragma unroll
  for (int j = 0; j < 8; ++j){
    __half hh = __float2half(vv[j]);
    __half ll = __float2half(vv[j] - __half2float(hh));
    HI.s[j] = __half_as_ushort(hh);
    LO.s[j] = __half_as_ushort(ll);
  }
  *(uint4*)(wsH + dhi) = HI.u;
  *(uint4*)(wsH + dlo) = LO.u;
}

// M=32/block, 256 blocks, 1 block/CU (v9 champion configuration, verbatim).
// POOL phases: big@0(33792) med@33792(16384)
// LSTM: h0h@0 [32][136]h (8704) | h1h@8704 | c0s@17408 (18432) | c1s@35840
//       | fc2p@54272 [32][8]f — zero weight streaming in t-loop (all B in 192 regs).
__global__ __attribute__((amdgpu_flat_work_group_size(512,512), amdgpu_waves_per_eu(2,2)))
void mkty_main(
    const float* __restrict__ data, const float* __restrict__ text_feature,
    const float* __restrict__ q_w, const float* __restrict__ q_b,
    const float* __restrict__ k_w, const float* __restrict__ k_b,
    const float* __restrict__ v_w, const float* __restrict__ v_b,
    const float* __restrict__ tp1_b,
    const float* __restrict__ tp2_w, const float* __restrict__ tp2_b,
    const float* __restrict__ g1_w, const float* __restrict__ g1_b,
    const float* __restrict__ g2_w, const float* __restrict__ g2_b,
    const float* __restrict__ w_ih0, const float* __restrict__ b_ih0,
    const float* __restrict__ b_hh0,
    const float* __restrict__ b_ih1, const float* __restrict__ b_hh1,
    const float* __restrict__ fc1_b,
    const float* __restrict__ fc2_w, const float* __restrict__ fc2_b,
    const __half* __restrict__ wsH, float* __restrict__ out)
{
  __shared__ float s_x[32][64];          // 8K
  __shared__ float s_gate[32][16];       // 2K
  __shared__ float s_rec[32][16];        // 2K
  __shared__ float s_res[32][16];        // 2K
  __shared__ float s_pred[32];
  __shared__ float ctab[64], stab[64];
  __shared__ __align__(16) unsigned char POOL[84992];  // >80K: 1 block/CU

  const int tid = threadIdx.x;
  const int w = tid >> 6, l = tid & 63;
  const int lm = l & 15, lq = l >> 4;
  const int s0blk = blockIdx.x * 32;

  { int s = tid >> 4, j = (tid*4) & 63;
    *(float4*)&s_x[s][j] = *(const float4*)(data + (size_t)(s0blk+s)*64 + j); }
  if (tid < 64){ float sv,cv; sincosf((float)tid*W0F,&sv,&cv);
    stab[tid] = (tid==32)?0.f:sv; ctab[tid]=cv; }
  __syncthreads();

  // ================= Phase A: h256 = lrelu(tf @ tp1_w^T + b1)  (MFMA, B f16-hi) =======
  {
    float* h256 = (float*)POOL;               // [32][260]
    uint32_t* tfp = (uint32_t*)(POOL + 33792);// [32][68] packed hi/lo
    const half8* T1h = (const half8*)(wsH + 425984);
    const int t0 = 2*w;
    f32x4 acc[2][2];
    #pragma unroll
    for (int mt=0; mt<2; ++mt)
      #pragma unroll
      for (int nt=0; nt<2; ++nt){ f32x4 z = {0.f,0.f,0.f,0.f}; acc[mt][nt] = z; }
    for (int kc = 0; kc < 1024; kc += 64){
      __syncthreads();
      { int s = tid >> 4, j0 = (tid & 15)*4;
        float4 v = *(const float4*)(text_feature + (size_t)(s0blk+s)*1024 + kc + j0);
        uint4 p; p.x = packhl(v.x); p.y = packhl(v.y); p.z = packhl(v.z); p.w = packhl(v.w);
        *(uint4*)&tfp[s*68 + j0] = p; }
      __syncthreads();
      #pragma unroll
      for (int ks = 0; ks < 2; ++ks){
        half8 Ah[2], Al[2];
        #pragma unroll
        for (int mt = 0; mt < 2; ++mt){
          const uint32_t* pp = &tfp[(mt*16+lm)*68 + ks*32 + lq*8];
          unpackA(*(const uint4*)pp, *(const uint4*)(pp+4), Ah[mt], Al[mt]);
        }
        int ksg = (kc >> 5) + ks;
        #pragma unroll
        for (int nt = 0; nt < 2; ++nt){
          int ci = ((t0+nt)*32 + ksg)*64 + l;
          half8 bh = T1h[ci];
          #pragma unroll
          for (int mt = 0; mt < 2; ++mt)
            acc[mt][nt] = mfma2(Ah[mt],Al[mt],bh,acc[mt][nt]);
        }
      }
    }
    #pragma unroll
    for (int nt = 0; nt < 2; ++nt){
      int n = (t0+nt)*16 + lm;
      float bb = tp1_b[n];
      #pragma unroll
      for (int mt = 0; mt < 2; ++mt)
        #pragma unroll
        for (int r = 0; r < 4; ++r)
          h256[(mt*16 + lq*4 + r)*260 + n] = lrelu(acc[mt][nt][r] + bb);
    }
  }
  __syncthreads();

  // ================= Phase B: tp = h256 @ tp2_w^T + b2  (VALU k-major) =================
  {
    const float* h256 = (const float*)POOL;
    int o = tid & 127, soct = tid >> 7, ss = soct*8;
    float acc8[8];
    #pragma unroll
    for (int i=0;i<8;++i) acc8[i]=0.f;
    const float4* w2r = (const float4*)(tp2_w + o*256);
    #pragma unroll 4
    for (int k4 = 0; k4 < 64; ++k4){
      float4 w4 = w2r[k4];
      #pragma unroll
      for (int i = 0; i < 8; ++i){
        float4 hv = *(const float4*)&h256[(ss+i)*260 + k4*4];
        acc8[i] += w4.x*hv.x; acc8[i] += w4.y*hv.y;
        acc8[i] += w4.z*hv.z; acc8[i] += w4.w*hv.w;
      }
    }
    __syncthreads();
    float* tpT = (float*)(POOL + 33792);   // [32][128]
    float bb = tp2_b[o];
    #pragma unroll
    for (int i=0;i<8;++i) tpT[(ss+i)*128 + o] = acc8[i] + bb;
  }
  __syncthreads();

  // ================= Phase C: DFT -> featT[64][32] =================
  {
    float* featT = (float*)POOL;
    #pragma unroll
    for (int i = 0; i < 2; ++i){
      int task = tid + 512*i;
      int s = task >> 5;
      int k = (task & 31) + 1;
      float re = 0.f, im = 0.f;
      #pragma unroll 8
      for (int n = 0; n < 64; ++n){
        float d = s_x[s][n];
        int m = (k*n) & 63;
        re += d*ctab[m]; im -= d*stab[m];
      }
      if (k == 32) im = 0.f;
      featT[(k-1)*32 + s] = sqrtf(re*re + im*im);
      featT[(31+k)*32 + s] = atan2f(im, re);
    }
  }
  __syncthreads();

  // ================= Phase D: Q,K,V ; QK = Q*K =================
  {
    const float* featT = (const float*)POOL;
    const float* tpT = (const float*)(POOL + 33792);
    float* QK = (float*)(POOL + 8192);
    float* V  = (float*)(POOL + 16384);
    #pragma unroll
    for (int i = 0; i < 4; ++i){
      int task = tid + 512*i;
      int s = task >> 6, o = task & 63;
      float q = q_b[o];
      const float* qwr = q_w + o*64;
      #pragma unroll 4
      for (int k = 0; k < 64; ++k) q += qwr[k]*featT[k*32 + s];
      float kk = k_b[o], vv = v_b[o];
      const float* kwr = k_w + o*128;
      const float* vwr = v_w + o*128;
      const float* tps = tpT + s*128;
      #pragma unroll 4
      for (int k = 0; k < 128; ++k){ kk += kwr[k]*tps[k]; vv += vwr[k]*tps[k]; }
      QK[s*64+o] = q*kk; V[s*64+o] = vv;
    }
  }
  __syncthreads();

  // ================= Phase E: adj = softmax(QK)*V (in-place in QK) =================
  if (tid < 32){
    float* QK = (float*)(POOL + 8192);
    const float* V = (const float*)(POOL + 16384);
    float mx = -1e30f;
    for (int o = 0; o < 64; ++o) mx = fmaxf(mx, QK[tid*64+o]);
    float sum = 0.f;
    for (int o = 0; o < 64; ++o){ float e = expf(QK[tid*64+o]-mx); QK[tid*64+o] = e; sum += e; }
    float inv = 1.f/sum;
    for (int o = 0; o < 64; ++o) QK[tid*64+o] *= inv*V[tid*64+o];
  }
  __syncthreads();

  // ================= Phase F: mid = lrelu(adj @ g1_w^T + b) =================
  {
    const float* ADJ = (const float*)(POOL + 8192);
    float* midT = (float*)(POOL + 33792);   // [32][128]
    int j = tid & 127, soct = tid >> 7, ss = soct*8;
    float accm[8];
    float bb = g1_b[j];
    #pragma unroll
    for (int i=0;i<8;++i) accm[i]=bb;
    const float* wr = g1_w + j*64;
    #pragma unroll 4
    for (int k = 0; k < 64; ++k){
      float ww = wr[k];
      #pragma unroll
      for (int i=0;i<8;++i) accm[i] += ww*ADJ[(ss+i)*64 + k];
    }
    #pragma unroll
    for (int i=0;i<8;++i) midT[(ss+i)*128 + j] = lrelu(accm[i]);
  }
  __syncthreads();

  // ================= Phase G: gate + recon =================
  {
    int s = tid >> 4, o = tid & 15;
    const float* midT = (const float*)(POOL + 33792);
    const float* ADJ = (const float*)(POOL + 8192);
    float acc = g2_b[o];
    const float* wr = g2_w + o*128;
    #pragma unroll 4
    for (int k = 0; k < 128; ++k) acc += wr[k]*midT[s*128 + k];
    float gate = sigf(acc);
    float sum = 0.f;
    float a32 = ADJ[s*64+31], p32 = ADJ[s*64+63];
    #pragma unroll
    for (int k = 1; k < 32; ++k){
      float amp = ADJ[s*64 + k-1];
      float ph  = ADJ[s*64 + 31+k];
      int m = (k*o) & 63;
      sum += amp*cosf(ph + (float)m*W0F);
    }
    float parity = (o&1)? -1.f : 1.f;
    s_gate[s][o] = gate;
    s_rec[s][o] = (2.f*sum + parity*a32*cosf(p32))*(1.f/64.f);
  }
  __syncthreads();

  // ===== LSTM prep: zero h planes (f16) + c planes (f32, stride-9 pad) =====
  { uint32_t* hz = (uint32_t*)POOL;
    for (int i = tid; i < 13568; i += 512) hz[i] = 0; }
  if (tid < 32) s_pred[tid] = s_x[tid][63];

  const int u = 16*w + lm;
  float bias0[4], wx0[4], bias1[4];
  #pragma unroll
  for (int T = 0; T < 4; ++T){
    int n = T*128 + u;
    bias0[T] = b_ih0[n] + b_hh0[n];
    wx0[T]   = w_ih0[n];
    bias1[T] = b_ih1[n] + b_hh1[n];
  }
  const float fb = fc1_b[u];
  const float wcol = fc2_w[u];
  const float fb2 = fc2_b[0];
  const half8* WH0h = (const half8*)(wsH);
  const half8* WI1h = (const half8*)(wsH + 131072);
  const half8* WH1h = (const half8*)(wsH + 262144);
  const half8* F1h  = (const half8*)(wsH + 393216);
  __half* h0h = (__half*)(POOL);            // [32][136]
  __half* h1h = (__half*)(POOL + 8704);     // [32][136]
  float*  c0s = (float*)(POOL + 17408);     // [tid][8] stride 9 (bank-spread)
  float*  c1s = (float*)(POOL + 35840);
  float*  fc2p = (float*)(POOL + 54272);    // [32][8]
  const int cbase = w*256 + l;

  // ---- permanent register cache: ALL LSTM B-fragments (3 x 16 half8 = 192 regs) ----
  half8 wh0[16], wi1[16], wh1[16];
  #pragma unroll
  for (int q = 0; q < 16; ++q){       // q = nt*4 + ks
    int nt = q >> 2, ks = q & 3;
    int ci = nt*2048 + ks*64 + cbase;
    wh0[q] = WH0h[ci];
    wi1[q] = WI1h[ci];
    wh1[q] = WH1h[ci];
  }
  #pragma unroll
  for (int q = 0; q < 16; ++q)
    asm volatile("" : "+v"(wh0[q]), "+v"(wi1[q]), "+v"(wh1[q]));
  __syncthreads();

  for (int t = 0; t < 80; ++t){
    // ---- GEMM0: gates0 = h0 @ WH0^T + x*w_ih0 + b  (zero global loads) ----
    float xv[2][4];
    #pragma unroll
    for (int mt = 0; mt < 2; ++mt)
      #pragma unroll
      for (int r = 0; r < 4; ++r){
        int m = mt*16 + lq*4 + r;
        xv[mt][r] = (t < 64) ? s_x[m][t] : s_pred[m];
      }
    f32x4 acc0[2][4];
    #pragma unroll
    for (int nt = 0; nt < 4; ++nt)
      #pragma unroll
      for (int mt = 0; mt < 2; ++mt){
        f32x4 a;
        #pragma unroll
        for (int r = 0; r < 4; ++r) a[r] = bias0[nt] + wx0[nt]*xv[mt][r];
        acc0[mt][nt] = a;
      }
    #pragma unroll
    for (int ks = 0; ks < 4; ++ks){
      half8 Ah[2];
      #pragma unroll
      for (int mt = 0; mt < 2; ++mt)
        Ah[mt] = *(const half8*)&h0h[(mt*16+lm)*136 + ks*32 + lq*8];
      #pragma unroll
      for (int nt = 0; nt < 4; ++nt)
        #pragma unroll
        for (int mt = 0; mt < 2; ++mt)
          acc0[mt][nt] = __builtin_amdgcn_mfma_f32_16x16x32_f16(Ah[mt], wh0[nt*4+ks], acc0[mt][nt], 0,0,0);
    }
    __syncthreads();   // S1: all GEMM0 reads of h0h done
    #pragma unroll
    for (int mt = 0; mt < 2; ++mt)
      #pragma unroll
      for (int r = 0; r < 4; ++r){
        int cix = tid*9 + mt*4 + r;
        float gi = acc0[mt][0][r], gf = acc0[mt][1][r];
        float gg = acc0[mt][2][r], go = acc0[mt][3][r];
        float c = sigf(gf)*c0s[cix] + sigf(gi)*tanh_fast(gg);
        float h = sigf(go)*tanh_fast(c);
        c0s[cix] = c;
        h0h[(mt*16 + lq*4 + r)*136 + u] = __float2half(h);
      }
    __syncthreads();   // S2: new h0 visible
    // ---- GEMM1: gates1 = h0new @ WI1^T + h1 @ WH1^T + b (B all in regs, 2 passes) ----
    f32x4 acc1[2][4];
    #pragma unroll
    for (int nt = 0; nt < 4; ++nt)
      #pragma unroll
      for (int mt = 0; mt < 2; ++mt){
        f32x4 a; float bb = bias1[nt];
        a[0]=bb; a[1]=bb; a[2]=bb; a[3]=bb;
        acc1[mt][nt] = a;
      }
    #pragma unroll
    for (int ks = 0; ks < 4; ++ks){
      half8 Ah[2];
      #pragma unroll
      for (int mt = 0; mt < 2; ++mt)
        Ah[mt] = *(const half8*)&h0h[(mt*16+lm)*136 + ks*32 + lq*8];
      #pragma unroll
      for (int nt = 0; nt < 4; ++nt)
        #pragma unroll
        for (int mt = 0; mt < 2; ++mt)
          acc1[mt][nt] = __builtin_amdgcn_mfma_f32_16x16x32_f16(Ah[mt], wi1[nt*4+ks], acc1[mt][nt], 0,0,0);
    }
    #pragma unroll
    for (int ks = 0; ks < 4; ++ks){
      half8 Ah[2];
      #pragma unroll
      for (int mt = 0; mt < 2; ++mt)
        Ah[mt] = *(const half8*)&h1h[(mt*16+lm)*136 + ks*32 + lq*8];
      #pragma unroll
      for (int nt = 0; nt < 4; ++nt)
        #pragma unroll
        for (int mt = 0; mt < 2; ++mt)
          acc1[mt][nt] = __builtin_amdgcn_mfma_f32_16x16x32_f16(Ah[mt], wh1[nt*4+ks], acc1[mt][nt], 0,0,0);
    }
    __syncthreads();   // S3: GEMM1 reads of h1h done
    #pragma unroll
    for (int mt = 0; mt < 2; ++mt)
      #pragma unroll
      for (int r = 0; r < 4; ++r){
        int cix = tid*9 + mt*4 + r;
        float gi = acc1[mt][0][r], gf = acc1[mt][1][r];
        float gg = acc1[mt][2][r], go = acc1[mt][3][r];
        float c = sigf(gf)*c1s[cix] + sigf(gi)*tanh_fast(gg);
        float h = sigf(go)*tanh_fast(c);
        c1s[cix] = c;
        h1h[(mt*16 + lq*4 + r)*136 + u] = __float2half(h);
      }
    __syncthreads();   // S4: new h1 visible

    if (t >= 64){
      // fc1: mid = lrelu(h1 @ fc1_w^T + b); fc2 via in-wave shuffle reduction
      f32x4 fa[2];
      #pragma unroll
      for (int mt = 0; mt < 2; ++mt){ f32x4 a; a[0]=fb;a[1]=fb;a[2]=fb;a[3]=fb; fa[mt]=a; }
      #pragma unroll
      for (int ks = 0; ks < 4; ++ks){
        half8 Ah[2];
        #pragma unroll
        for (int mt = 0; mt < 2; ++mt)
          Ah[mt] = *(const half8*)&h1h[(mt*16+lm)*136 + ks*32 + lq*8];
        int ci = (w*4 + ks)*64 + l;
        half8 bh = F1h[ci];
        #pragma unroll
        for (int mt = 0; mt < 2; ++mt)
          fa[mt] = __builtin_amdgcn_mfma_f32_16x16x32_f16(Ah[mt], bh, fa[mt], 0,0,0);
      }
      float pr[2][4];
      #pragma unroll
      for (int mt = 0; mt < 2; ++mt)
        #pragma unroll
        for (int r = 0; r < 4; ++r){
          float p = lrelu(fa[mt][r]) * wcol;
          p += __shfl_xor(p, 1, 16);
          p += __shfl_xor(p, 2, 16);
          p += __shfl_xor(p, 4, 16);
          p += __shfl_xor(p, 8, 16);
          pr[mt][r] = p;
        }
      if (lm == 0){
        #pragma unroll
        for (int mt = 0; mt < 2; ++mt)
          #pragma unroll
          for (int r = 0; r < 4; ++r)
            fc2p[(mt*16 + lq*4 + r)*8 + w] = pr[mt][r];
      }
      __syncthreads(); // S5
      if (tid < 32){
        float s = fb2;
        #pragma unroll
        for (int j = 0; j < 8; ++j) s += fc2p[tid*8 + j];
        s_pred[tid] = s;
        s_res[tid][t-64] = s;
      }
      __syncthreads(); // S6: s_pred visible for next step
    }
  }

  // ---- final combine ----
  {
    int s = tid >> 4, d = tid & 15;
    float g = s_gate[s][d];
    out[(size_t)blockIdx.x*512 + tid] = g*s_res[s][d] + (1.f - g)*s_rec[s][d];
  }
}

extern "C" void kernel_launch(void* const* d_in, const int* in_sizes, int n_in,
                              void* d_out, int out_size, void* d_ws, size_t ws_size,
                              hipStream_t stream){
  const float* data =(const float*)d_in[0];
  const float* tf   =(const float*)d_in[1];
  const float* q_w  =(const float*)d_in[2];  const float* q_b  =(const float*)d_in[3];
  const float* k_w  =(const float*)d_in[4];  const float* k_b  =(const float*)d_in[5];
  const float* v_w  =(const float*)d_in[6];  const float* v_b  =(const float*)d_in[7];
  const float* tp1_w=(const float*)d_in[8];  const float* tp1_b=(const float*)d_in[9];
  const float* tp2_w=(const float*)d_in[10]; const float* tp2_b=(const float*)d_in[11];
  const float* g1_w =(const float*)d_in[12]; const float* g1_b =(const float*)d_in[13];
  const float* g2_w =(const float*)d_in[14]; const float* g2_b =(const float*)d_in[15];
  const float* w_ih0=(const float*)d_in[16]; const float* b_ih0=(const float*)d_in[17];
  const float* w_hh0=(const float*)d_in[18]; const float* b_hh0=(const float*)d_in[19];
  const float* w_ih1=(const float*)d_in[20]; const float* b_ih1=(const float*)d_in[21];
  const float* w_hh1=(const float*)d_in[22]; const float* b_hh1=(const float*)d_in[23];
  const float* fc1_w=(const float*)d_in[24]; const float* fc1_b=(const float*)d_in[25];
  const float* fc2_w=(const float*)d_in[26]; const float* fc2_b=(const float*)d_in[27];
  float* out=(float*)d_out;
  __half* wsH = (__half*)d_ws;

  convert_w<<<232,256,0,stream>>>(w_hh0, w_ih1, w_hh1, fc1_w, tp1_w, wsH);
  mkty_main<<<256,512,0,stream>>>(data, tf, q_w,q_b, k_w,k_b, v_w,v_b,
                                  tp1_b, tp2_w,tp2_b, g1_w,g1_b, g2_w,g2_b,
                                  w_ih0,b_ih0,b_hh0, b_ih1,b_hh1,
                                  fc1_b, fc2_w,fc2_b, wsH, out);
}